// Round 1
// baseline (72.891 us; speedup 1.0000x reference)
//
#include <hip/hip_runtime.h>
#include <stdint.h>
#include <stddef.h>

#define BATCH 8192
#define DIM   256

// exp2-domain scale: 1000 * log2(e)
#define EXP2_SCALE 1442.6950408889634f
#define LN2F       0.6931471805599453f

typedef short short8 __attribute__((ext_vector_type(8)));   // 8 bf16 (4 VGPRs)
typedef float f32x16 __attribute__((ext_vector_type(16)));  // 32x32 MFMA acc

// ---------- helpers ----------
static __device__ __forceinline__ unsigned short f2bf(float f) {
  union { float f; unsigned int u; } v; v.f = f;
  unsigned int u = v.u;
  unsigned int r = (u + 0x7fffu + ((u >> 16) & 1u)) >> 16;  // RNE
  return (unsigned short)r;
}

// global -> LDS staging of one 32-row x 512B tile (16 KB), linear LDS dest,
// source pre-swizzled with byte ^= ((row&7)<<4) so ds_read_b128 of B frags
// is bank-conflict-spread (rule 21: swizzle source+read, dest stays linear).
static __device__ __forceinline__ void stage_tile(const uint8_t* __restrict__ src,
                                                  uint8_t* dst, int tid) {
  const int lane = tid & 63;
  const int w    = tid >> 6;
#pragma unroll
  for (int c = 0; c < 4; ++c) {
    int L  = w * 4096 + c * 1024 + lane * 16;       // linear byte in tile
    int Ls = L ^ (((L >> 9) & 7) << 4);             // swizzled source byte
    __builtin_amdgcn_global_load_lds(
        (const __attribute__((address_space(1))) void*)(src + Ls),
        (__attribute__((address_space(3))) void*)(dst + w * 4096 + c * 1024),
        16, 0, 0);
  }
}

// ---------- pass 1: normalize, exact fp32 positives, bf16 convert ----------
__global__ __launch_bounds__(256) void prep_kernel(
    const float* __restrict__ p1, const float* __restrict__ p2,
    unsigned short* __restrict__ Zi, unsigned short* __restrict__ Zj,
    float* __restrict__ pos) {
  const int lane = threadIdx.x & 63;
  const int w    = threadIdx.x >> 6;
  const int row  = blockIdx.x * 4 + w;   // one wave per row

  const float4 x1 = ((const float4*)p1)[row * 64 + lane];
  const float4 x2 = ((const float4*)p2)[row * 64 + lane];
  float ss1 = x1.x * x1.x + x1.y * x1.y + x1.z * x1.z + x1.w * x1.w;
  float ss2 = x2.x * x2.x + x2.y * x2.y + x2.z * x2.z + x2.w * x2.w;
  float d   = x1.x * x2.x + x1.y * x2.y + x1.z * x2.z + x1.w * x2.w;
#pragma unroll
  for (int m = 1; m < 64; m <<= 1) {
    ss1 += __shfl_xor(ss1, m);
    ss2 += __shfl_xor(ss2, m);
    d   += __shfl_xor(d, m);
  }
  const float n1 = fmaxf(sqrtf(ss1), 1e-12f);
  const float n2 = fmaxf(sqrtf(ss2), 1e-12f);
  if (lane == 0) pos[row] = d / (n1 * n2);          // exact fp32 diagonal

  const float sA = EXP2_SCALE / n1;  // fold temp+log2(e) into A side
  const float sB = 1.0f / n2;
  ushort4 u1, u2;
  u1.x = f2bf(x1.x * sA); u1.y = f2bf(x1.y * sA);
  u1.z = f2bf(x1.z * sA); u1.w = f2bf(x1.w * sA);
  u2.x = f2bf(x2.x * sB); u2.y = f2bf(x2.y * sB);
  u2.z = f2bf(x2.z * sB); u2.w = f2bf(x2.w * sB);
  ((ushort4*)Zi)[row * 64 + lane] = u1;
  ((ushort4*)Zj)[row * 64 + lane] = u2;
}

// ---------- pass 2: fused MFMA GEMM + online logsumexp ----------
// grid = 64 row-blocks (128 rows: 4 waves x 32) x 8 j-chunks (1024 cols each).
// chunk = bid&7 -> all blocks of one chunk land on one XCD (L2-local Zj).
__global__ __launch_bounds__(256, 2) void lse_kernel(
    const unsigned short* __restrict__ Zi, const unsigned short* __restrict__ Zj,
    float2* __restrict__ partial) {
  const int bid   = blockIdx.x;
  const int chunk = bid & 7;
  const int rb    = bid >> 3;
  const int tid   = threadIdx.x;
  const int lane  = tid & 63;
  const int w     = tid >> 6;
  const int r32   = lane & 31;
  const int h     = lane >> 5;
  const int rowBase = rb * 128 + w * 32;

  __shared__ __align__(16) uint8_t lds[2][16384];  // 2 x (32 rows x 512B)

  // A fragments for this wave's 32 rows, all of K=256, kept in registers.
  // 32x32x16 A layout: m = lane%32, k = 16t + 8*(lane/32) + e  (k-permutation
  // cancels between A and B since both use the mirrored layout).
  short8 a[16];
  const unsigned short* zia = Zi + (size_t)(rowBase + r32) * DIM + h * 8;
#pragma unroll
  for (int t = 0; t < 16; ++t) a[t] = *(const short8*)(zia + t * 16);

  // per-(lane,reg) online lse state: 16 (row,col-slot) slots
  float m[16], l[16];
#pragma unroll
  for (int r = 0; r < 16; ++r) { m[r] = -1e30f; l[r] = 0.0f; }

  const uint8_t* src = (const uint8_t*)Zj + (size_t)chunk * (1024 * 512);
  const int xm = (r32 & 7) << 4;

  stage_tile(src, &lds[0][0], tid);
  __syncthreads();

  int cur = 0;
  for (int it = 0; it < 32; ++it) {
    if (it + 1 < 32) stage_tile(src + (size_t)(it + 1) * 16384, &lds[cur ^ 1][0], tid);

    f32x16 acc = {};
#pragma unroll
    for (int t = 0; t < 16; ++t) {
      const int boff = (t * 32 + h * 16) ^ xm;  // swizzled read (matches stage)
      short8 b = *(const short8*)(&lds[cur][r32 * 512 + boff]);
      acc = __builtin_amdgcn_mfma_f32_32x32x16_bf16(a[t], b, acc, 0, 0, 0);
    }
    // online lse update; acc already in exp2 domain (scale folded into Zi)
#pragma unroll
    for (int r = 0; r < 16; ++r) {
      const float s  = acc[r];
      const float mn = fmaxf(m[r], s);
      l[r] = l[r] * __builtin_amdgcn_exp2f(m[r] - mn) +
             __builtin_amdgcn_exp2f(s - mn);
      m[r] = mn;
    }
    __syncthreads();  // drains this wave's global_load_lds (vmcnt) + orders LDS
    cur ^= 1;
  }

  // combine the 32 column-slots of each row (lanes 0-31 / 32-63 independent)
#pragma unroll
  for (int r = 0; r < 16; ++r) {
#pragma unroll
    for (int msk = 1; msk < 32; msk <<= 1) {
      const float mo = __shfl_xor(m[r], msk);
      const float lo = __shfl_xor(l[r], msk);
      const float mn = fmaxf(m[r], mo);
      l[r] = l[r] * __builtin_amdgcn_exp2f(m[r] - mn) +
             lo   * __builtin_amdgcn_exp2f(mo - mn);
      m[r] = mn;
    }
    if (r32 == 0) {
      // verified 32x32 C/D layout: row = (reg&3) + 8*(reg>>2) + 4*(lane>>5)
      const int row = rowBase + (r & 3) + 8 * (r >> 2) + 4 * h;
      partial[(size_t)chunk * BATCH + row] = make_float2(m[r], l[r]);
    }
  }
}

// ---------- pass 3: combine chunk partials, reduce to 2 scalars ----------
__global__ __launch_bounds__(1024) void finalize_kernel(
    const float2* __restrict__ partial, const float* __restrict__ pos,
    float* __restrict__ out) {
  const int tid = threadIdx.x;
  float lsum = 0.0f, psum = 0.0f;
  for (int row = tid; row < BATCH; row += 1024) {
    float m = -1e30f, l = 0.0f;
#pragma unroll
    for (int c = 0; c < 8; ++c) {
      const float2 p = partial[(size_t)c * BATCH + row];
      const float mn = fmaxf(m, p.x);
      l = l * __builtin_amdgcn_exp2f(m - mn) +
          p.y * __builtin_amdgcn_exp2f(p.x - mn);
      m = mn;
    }
    const float lse = LN2F * (m + __builtin_amdgcn_logf(l));  // natural-log lse
    const float pv  = pos[row];
    lsum += lse - 1000.0f * pv;
    psum += pv;
  }
#pragma unroll
  for (int msk = 1; msk < 64; msk <<= 1) {
    lsum += __shfl_xor(lsum, msk);
    psum += __shfl_xor(psum, msk);
  }
  __shared__ float sl[16], sp[16];
  const int w = tid >> 6, lane = tid & 63;
  if (lane == 0) { sl[w] = lsum; sp[w] = psum; }
  __syncthreads();
  if (tid == 0) {
    float L = 0.0f, P = 0.0f;
#pragma unroll
    for (int i = 0; i < 16; ++i) { L += sl[i]; P += sp[i]; }
    out[0] = L / (float)BATCH;   // loss
    out[1] = P;                  // sum(positives)
  }
}

extern "C" void kernel_launch(void* const* d_in, const int* in_sizes, int n_in,
                              void* d_out, int out_size, void* d_ws, size_t ws_size,
                              hipStream_t stream) {
  const float* p1 = (const float*)d_in[0];
  const float* p2 = (const float*)d_in[1];
  float* out = (float*)d_out;
  uint8_t* ws = (uint8_t*)d_ws;

  unsigned short* Zi = (unsigned short*)(ws);                                // 4 MB
  unsigned short* Zj = (unsigned short*)(ws + (size_t)4 * 1024 * 1024);      // 4 MB
  float* pos         = (float*)(ws + (size_t)8 * 1024 * 1024);               // 32 KB
  float2* partial    = (float2*)(ws + (size_t)8 * 1024 * 1024 + 64 * 1024);  // 512 KB

  prep_kernel<<<dim3(2048), dim3(256), 0, stream>>>(p1, p2, Zi, Zj, pos);
  lse_kernel<<<dim3(512), dim3(256), 0, stream>>>(Zi, Zj, partial);
  finalize_kernel<<<dim3(1), dim3(1024), 0, stream>>>(partial, pos, out);
}

// Round 2
// 53.857 us; speedup vs baseline: 1.3534x; 1.3534x over previous
//
#include <hip/hip_runtime.h>
#include <stdint.h>
#include <stddef.h>

#define BATCH 8192
#define DIM   256

// exp2-domain scale: 1000 * log2(e)
#define EXP2_SCALE 1442.6950408889634f
#define LN2F       0.6931471805599453f

typedef short short8 __attribute__((ext_vector_type(8)));   // 8 bf16 (4 VGPRs)
typedef float f32x16 __attribute__((ext_vector_type(16)));  // 32x32 MFMA acc

// ---------- helpers ----------
static __device__ __forceinline__ unsigned short f2bf(float f) {
  union { float f; unsigned int u; } v; v.f = f;
  unsigned int u = v.u;
  unsigned int r = (u + 0x7fffu + ((u >> 16) & 1u)) >> 16;  // RNE
  return (unsigned short)r;
}

// global -> LDS staging of one 32-row x 512B tile (16 KB), linear LDS dest,
// source pre-swizzled with byte ^= ((row&7)<<4) so ds_read_b128 of A frags
// is bank-conflict-spread (rule 21: swizzle source+read, dest stays linear).
static __device__ __forceinline__ void stage_tile(const uint8_t* __restrict__ src,
                                                  uint8_t* dst, int tid) {
  const int lane = tid & 63;
  const int w    = tid >> 6;
#pragma unroll
  for (int c = 0; c < 4; ++c) {
    int L  = w * 4096 + c * 1024 + lane * 16;       // linear byte in tile
    int Ls = L ^ (((L >> 9) & 7) << 4);             // swizzled source byte
    __builtin_amdgcn_global_load_lds(
        (const __attribute__((address_space(1))) void*)(src + Ls),
        (__attribute__((address_space(3))) void*)(dst + w * 4096 + c * 1024),
        16, 0, 0);
  }
}

// ---------- pass 1: normalize, exact fp32 positives, bf16 convert ----------
__global__ __launch_bounds__(256) void prep_kernel(
    const float* __restrict__ p1, const float* __restrict__ p2,
    unsigned short* __restrict__ Zi, unsigned short* __restrict__ Zj,
    float* __restrict__ pos) {
  const int lane = threadIdx.x & 63;
  const int w    = threadIdx.x >> 6;
  const int row  = blockIdx.x * 4 + w;   // one wave per row

  const float4 x1 = ((const float4*)p1)[row * 64 + lane];
  const float4 x2 = ((const float4*)p2)[row * 64 + lane];
  float ss1 = x1.x * x1.x + x1.y * x1.y + x1.z * x1.z + x1.w * x1.w;
  float ss2 = x2.x * x2.x + x2.y * x2.y + x2.z * x2.z + x2.w * x2.w;
  float d   = x1.x * x2.x + x1.y * x2.y + x1.z * x2.z + x1.w * x2.w;
#pragma unroll
  for (int m = 1; m < 64; m <<= 1) {
    ss1 += __shfl_xor(ss1, m);
    ss2 += __shfl_xor(ss2, m);
    d   += __shfl_xor(d, m);
  }
  const float n1 = fmaxf(sqrtf(ss1), 1e-12f);
  const float n2 = fmaxf(sqrtf(ss2), 1e-12f);
  if (lane == 0) pos[row] = d / (n1 * n2);          // exact fp32 diagonal

  const float sA = EXP2_SCALE / n1;  // fold temp+log2(e) into Zi side
  const float sB = 1.0f / n2;
  ushort4 u1, u2;
  u1.x = f2bf(x1.x * sA); u1.y = f2bf(x1.y * sA);
  u1.z = f2bf(x1.z * sA); u1.w = f2bf(x1.w * sA);
  u2.x = f2bf(x2.x * sB); u2.y = f2bf(x2.y * sB);
  u2.z = f2bf(x2.z * sB); u2.w = f2bf(x2.w * sB);
  ((ushort4*)Zi)[row * 64 + lane] = u1;
  ((ushort4*)Zj)[row * 64 + lane] = u2;
}

// ---------- online lse update for one 16-score acc block ----------
static __device__ __forceinline__ void lse_update(const f32x16& acc,
                                                  float& m, float& l) {
  // pairwise max tree
  float mx[8];
#pragma unroll
  for (int r = 0; r < 8; ++r) mx[r] = fmaxf(acc[r], acc[r + 8]);
#pragma unroll
  for (int r = 0; r < 4; ++r) mx[r] = fmaxf(mx[r], mx[r + 4]);
  const float tmax = fmaxf(fmaxf(mx[0], mx[1]), fmaxf(mx[2], mx[3]));
  const float mn = fmaxf(m, tmax);
  // 4 independent partial sums to break the dependent-add chain
  float s0 = 0.f, s1 = 0.f, s2 = 0.f, s3 = 0.f;
#pragma unroll
  for (int r = 0; r < 16; r += 4) {
    s0 += __builtin_amdgcn_exp2f(acc[r + 0] - mn);
    s1 += __builtin_amdgcn_exp2f(acc[r + 1] - mn);
    s2 += __builtin_amdgcn_exp2f(acc[r + 2] - mn);
    s3 += __builtin_amdgcn_exp2f(acc[r + 3] - mn);
  }
  l = l * __builtin_amdgcn_exp2f(m - mn) + ((s0 + s1) + (s2 + s3));
  m = mn;
}

// ---------- pass 2: fused MFMA GEMM + online logsumexp ----------
// Swapped operands: acc = mfma(A=Zj_frag, B=Zi_frag) -> D[j][i], col(lane&31)=i.
// Each lane owns TWO i rows (i-blocks 0/1), scalar (m,l) state per row.
// grid = 32 row-blocks (256 i: 4 waves x 64) x 16 j-chunks (512 cols each).
// chunk = bid&15 -> chunk c lands on XCD c%8 (Zj slice 512KB L2-resident).
__global__ __launch_bounds__(256, 2) void lse_kernel(
    const unsigned short* __restrict__ Zi, const unsigned short* __restrict__ Zj,
    float* __restrict__ plse) {
  const int bid   = blockIdx.x;
  const int chunk = bid & 15;
  const int rb    = bid >> 4;
  const int tid   = threadIdx.x;
  const int lane  = tid & 63;
  const int w     = tid >> 6;
  const int r32   = lane & 31;
  const int h     = lane >> 5;
  const int iBase = rb * 256 + w * 64;

  __shared__ __align__(16) uint8_t lds[2][16384];  // 2 x (32 j-rows x 512B)

  // B fragments: this lane's two i rows (n = lane&31), all of K=256.
  // k = 16t + 8h + e for both A and B -> k-permutation cancels.
  short8 b0[16], b1[16];
  const unsigned short* z0 = Zi + (size_t)(iBase + r32) * DIM + h * 8;
#pragma unroll
  for (int t = 0; t < 16; ++t) {
    b0[t] = *(const short8*)(z0 + t * 16);
    b1[t] = *(const short8*)(z0 + 32 * DIM + t * 16);
  }

  float m0 = -1e30f, l0 = 0.0f, m1 = -1e30f, l1 = 0.0f;

  const uint8_t* src = (const uint8_t*)Zj + (size_t)chunk * (512 * 512);
  const int xm = (r32 & 7) << 4;

  stage_tile(src, &lds[0][0], tid);
  __syncthreads();

  int cur = 0;
  for (int it = 0; it < 16; ++it) {
    if (it + 1 < 16) stage_tile(src + (size_t)(it + 1) * 16384, &lds[cur ^ 1][0], tid);

    f32x16 acc0 = {}, acc1 = {};
#pragma unroll
    for (int t = 0; t < 16; ++t) {
      const int boff = (t * 32 + h * 16) ^ xm;  // swizzled read (matches stage)
      short8 af = *(const short8*)(&lds[cur][r32 * 512 + boff]);
      acc0 = __builtin_amdgcn_mfma_f32_32x32x16_bf16(af, b0[t], acc0, 0, 0, 0);
      acc1 = __builtin_amdgcn_mfma_f32_32x32x16_bf16(af, b1[t], acc1, 0, 0, 0);
    }
    lse_update(acc0, m0, l0);
    lse_update(acc1, m1, l1);
    __syncthreads();  // drains next-tile global_load_lds + orders LDS reuse
    cur ^= 1;
  }

  // lanes l and l+32 hold the same i with complementary j-subsets: one swap
#pragma unroll
  for (int p = 0; p < 2; ++p) {
    float& m = p ? m1 : m0;
    float& l = p ? l1 : l0;
    const float mo = __shfl_xor(m, 32);
    const float lo = __shfl_xor(l, 32);
    const float mn = fmaxf(m, mo);
    l = l * __builtin_amdgcn_exp2f(m - mn) + lo * __builtin_amdgcn_exp2f(mo - mn);
    m = mn;
    if (h == 0) {
      const int i = iBase + p * 32 + r32;
      plse[(size_t)chunk * BATCH + i] = m + __builtin_amdgcn_logf(l);  // log2-lse
    }
  }
}

// ---------- pass 3a: per-row combine of 16 chunk lse's + block partials ----
__global__ __launch_bounds__(256) void finalize1_kernel(
    const float* __restrict__ plse, const float* __restrict__ pos,
    float2* __restrict__ bpart) {
  const int tid = threadIdx.x;
  const int row = blockIdx.x * 256 + tid;
  float v[16];
#pragma unroll
  for (int c = 0; c < 16; ++c) v[c] = plse[(size_t)c * BATCH + row];
  float M = v[0];
#pragma unroll
  for (int c = 1; c < 16; ++c) M = fmaxf(M, v[c]);
  float S = 0.0f;
#pragma unroll
  for (int c = 0; c < 16; ++c) S += __builtin_amdgcn_exp2f(v[c] - M);
  const float lse = LN2F * (M + __builtin_amdgcn_logf(S));  // natural-log lse
  const float pv  = pos[row];
  float lsum = lse - 1000.0f * pv;
  float psum = pv;
#pragma unroll
  for (int msk = 1; msk < 64; msk <<= 1) {
    lsum += __shfl_xor(lsum, msk);
    psum += __shfl_xor(psum, msk);
  }
  __shared__ float sl[4], sp[4];
  const int w = tid >> 6, lane = tid & 63;
  if (lane == 0) { sl[w] = lsum; sp[w] = psum; }
  __syncthreads();
  if (tid == 0) {
    bpart[blockIdx.x] = make_float2(sl[0] + sl[1] + sl[2] + sl[3],
                                    sp[0] + sp[1] + sp[2] + sp[3]);
  }
}

// ---------- pass 3b: reduce 32 block partials to 2 scalars ----------
__global__ __launch_bounds__(64) void finalize2_kernel(
    const float2* __restrict__ bpart, float* __restrict__ out) {
  const int tid = threadIdx.x;
  float L = 0.0f, P = 0.0f;
  if (tid < 32) { const float2 v = bpart[tid]; L = v.x; P = v.y; }
#pragma unroll
  for (int msk = 1; msk < 64; msk <<= 1) {
    L += __shfl_xor(L, msk);
    P += __shfl_xor(P, msk);
  }
  if (tid == 0) {
    out[0] = L / (float)BATCH;  // loss
    out[1] = P;                 // sum(positives)
  }
}

extern "C" void kernel_launch(void* const* d_in, const int* in_sizes, int n_in,
                              void* d_out, int out_size, void* d_ws, size_t ws_size,
                              hipStream_t stream) {
  const float* p1 = (const float*)d_in[0];
  const float* p2 = (const float*)d_in[1];
  float* out = (float*)d_out;
  uint8_t* ws = (uint8_t*)d_ws;

  unsigned short* Zi = (unsigned short*)(ws);                                // 4 MB
  unsigned short* Zj = (unsigned short*)(ws + (size_t)4 * 1024 * 1024);      // 4 MB
  float* pos         = (float*)(ws + (size_t)8 * 1024 * 1024);               // 32 KB
  float2* bpart      = (float2*)(ws + (size_t)8 * 1024 * 1024 + 32 * 1024);  // 256 B
  float* plse        = (float*)(ws + (size_t)8 * 1024 * 1024 + 64 * 1024);   // 512 KB

  prep_kernel<<<dim3(2048), dim3(256), 0, stream>>>(p1, p2, Zi, Zj, pos);
  lse_kernel<<<dim3(512), dim3(256), 0, stream>>>(Zi, Zj, plse);
  finalize1_kernel<<<dim3(32), dim3(256), 0, stream>>>(plse, pos, bpart);
  finalize2_kernel<<<dim3(1), dim3(64), 0, stream>>>(bpart, out);
}